// Round 5
// baseline (225.386 us; speedup 1.0000x reference)
//
#include <hip/hip_runtime.h>
#include <math.h>

#define BB 64
#define TT 256
#define KK 32
#define VV 32
#define CH 32                    // chunk rows per block
#define PH 32                    // steps per phase
#define ROWS (CH + PH)           // 64 rows covered per block
#define NPHASE ((TT + KK) / PH)  // 9 phases * 32 = 288 steps
#define BPB (TT / CH)            // 8 chunks per batch
#define NW (ROWS / 16)           // 4 waves per block

// workspace layout (floats)
#define RW_OFF    0                       // K*K
#define WOP_OFF   1024                    // 37*K
#define ATOM_OFF  2240                    // B*T*K
#define STATE_OFF (ATOM_OFF + BB*TT*KK)   // B*T*K (halo handoff rows only)
#define FLAG_OFF  (STATE_OFF + BB*TT*KK)  // BB*BPB ints

typedef __attribute__((ext_vector_type(8))) short short8;
typedef __attribute__((ext_vector_type(4))) float floatx4;

__device__ __forceinline__ float myrelu(float z) {
    // 0.01*z + 0.99*clamp(z,0,1)
    return fmaf(0.01f, z, 0.99f * __builtin_amdgcn_fmed3f(z, 0.f, 1.f));
}
__device__ __forceinline__ ushort f2bf(float f) {
    union { float f; unsigned int u; } v; v.f = f;
    unsigned int r = v.u + 0x7fffu + ((v.u >> 16) & 1u);
    return (ushort)(r >> 16);
}
__device__ __forceinline__ float dpp_shl1(float v) {
    // lane n <- lane n+1 within each 16-lane row; top lane of row -> 0
    return __int_as_float(__builtin_amdgcn_update_dpp(
        0, __float_as_int(v), 0x101 /*row_shl:1*/, 0xF, 0xF, true));
}

// --- softmaxes of w_op (32 x 37) and w_right (32 x 33) ---
__global__ void prep_kernel(const float* __restrict__ w_right,
                            const float* __restrict__ w_op,
                            float* __restrict__ ws) {
    int tid = threadIdx.x;
    float* rw  = ws + RW_OFF;   // rw[k*K + j] = right_w[k][j] = softmax(w_right)[j][k]
    float* wop = ws + WOP_OFF;  // wop[i*K + k] = sm_op[k][i]
    if (tid < KK) {
        float v[37];
        float m = -1e30f;
        #pragma unroll
        for (int i = 0; i < 37; ++i) { v[i] = w_op[tid * 37 + i]; m = fmaxf(m, v[i]); }
        float s = 0.f;
        #pragma unroll
        for (int i = 0; i < 37; ++i) { v[i] = expf(v[i] - m); s += v[i]; }
        float inv = 1.f / s;
        #pragma unroll
        for (int i = 0; i < 37; ++i) wop[i * KK + tid] = v[i] * inv;
    } else if (tid < 2 * KK) {
        int r = tid - KK;
        float v[KK + 1];
        float m = -1e30f;
        #pragma unroll
        for (int i = 0; i <= KK; ++i) { v[i] = w_right[r * (KK + 1) + i]; m = fmaxf(m, v[i]); }
        float s = 0.f;
        #pragma unroll
        for (int i = 0; i <= KK; ++i) { v[i] = expf(v[i] - m); s += v[i]; }
        float inv = 1.f / s;
        #pragma unroll
        for (int c = 0; c < KK; ++c) rw[c * KK + r] = v[c] * inv;
    }
}

// --- atom_x = x @ atom_w ; zero the handshake flags ---
__global__ void atomx_kernel(const float* __restrict__ x, float* __restrict__ ws) {
    const float* aw = ws + WOP_OFF + 5 * KK;
    float* atom = ws + ATOM_OFF;
    int tid = threadIdx.x;
    if (blockIdx.x < 2) ((int*)(ws + FLAG_OFF))[blockIdx.x * 256 + tid] = 0;
    int k  = tid & (KK - 1);
    int bt = blockIdx.x * 8 + (tid >> 5);
    const float* xrow = x + bt * VV;
    float acc = 0.f;
    #pragma unroll
    for (int v = 0; v < VV; ++v) acc = fmaf(xrow[v], aw[v * KK + k], acc);
    atom[bt * KK + k] = acc;
}

// --- all 288 steps in one cooperative kernel; neighbor-flag phase handoff ---
__global__ __launch_bounds__(256, 2)
void phase_all_kernel(float* __restrict__ ws, float* __restrict__ out) {
    __shared__ float brow[2][NW + 1][36];   // tile-boundary rows, dbuf

    const float* rw   = ws + RW_OFF;
    const float* wop  = ws + WOP_OFF;
    const float* atom = ws + ATOM_OFF;
    float*      state = ws + STATE_OFF;
    int*        flags = (int*)(ws + FLAG_OFF);

    int tid  = threadIdx.x;
    int lane = tid & 63;
    int rt   = tid >> 6;        // wave = row-tile 0..3
    int lr   = lane & 15;
    int hi   = lane >> 4;
    int b  = blockIdx.x / BPB;
    int c  = blockIdx.x % BPB;
    int lo = c * CH;
    int t0 = lo + rt * 16 + lr;            // this lane's global row
    bool active = (lo + rt * 16) < TT;

    for (int i = tid; i < 2 * (NW + 1) * 36; i += 256)
        (&brow[0][0][0])[i] = 0.f;

    float* gs = state + (size_t)b * TT * KK;

    float y[8];
    #pragma unroll
    for (int q = 0; q < 8; ++q) y[q] = 0.f;

    // per-lane constants for cols hi*8..hi*8+7 (folded form):
    // z = acc(c0p + rt*(w2+w4)) + le*d1p + nx*w4n + med3(le+nx,1,2)*w4c + xl*w3
    float c0p[8], d1p[8], w3v[8], w4n[8], w4c[8];
    {
        float av[8] = {0, 0, 0, 0, 0, 0, 0, 0};
        if (active) {
            float4 a0 = *reinterpret_cast<const float4*>(&atom[((size_t)b * TT + t0) * KK + hi * 8]);
            float4 a1 = *reinterpret_cast<const float4*>(&atom[((size_t)b * TT + t0) * KK + hi * 8 + 4]);
            av[0] = a0.x; av[1] = a0.y; av[2] = a0.z; av[3] = a0.w;
            av[4] = a1.x; av[5] = a1.y; av[6] = a1.z; av[7] = a1.w;
        }
        #pragma unroll
        for (int q = 0; q < 8; ++q) {
            int j = hi * 8 + q;
            float w1 = wop[1 * KK + j];
            float w2 = wop[2 * KK + j];
            float w3 = wop[3 * KK + j];
            float w4 = wop[4 * KK + j];
            c0p[q] = av[q] + w1 - w2 - w4;
            d1p[q] = (w2 - w1) + 0.01f * w4;
            w4n[q] = 0.01f * w4;
            w4c[q] = 0.99f * w4;
            w3v[q] = w3;
        }
    }

    // A fragments scaled by (w2+w4) per output column; col0(m)=(m>>2)*8+(m&3)
    short8 af0, af1;
    {
        int col0 = ((lr >> 2) << 3) | (lr & 3);
        float s0 = wop[2 * KK + col0]     + wop[4 * KK + col0];
        float s1 = wop[2 * KK + col0 + 4] + wop[4 * KK + col0 + 4];
        #pragma unroll
        for (int q = 0; q < 8; ++q) {
            af0[q] = (short)f2bf(rw[(hi * 8 + q) * KK + col0] * s0);
            af1[q] = (short)f2bf(rw[(hi * 8 + q) * KK + col0 + 4] * s1);
        }
    }

    int pidx = ((lane + 16) & 63) << 2;   // bpermute byte addr for lane+16
    __syncthreads();

    for (int p = 0; p < NPHASE; ++p) {
        for (int s = 0; s < PH; ++s) {
            int cur = s & 1;
            if (active) {
                unsigned bw0, bw1, bw2, bw3;
                asm("v_cvt_pk_bf16_f32 %0, %1, %2" : "=v"(bw0) : "v"(y[0]), "v"(y[1]));
                asm("v_cvt_pk_bf16_f32 %0, %1, %2" : "=v"(bw1) : "v"(y[2]), "v"(y[3]));
                asm("v_cvt_pk_bf16_f32 %0, %1, %2" : "=v"(bw2) : "v"(y[4]), "v"(y[5]));
                asm("v_cvt_pk_bf16_f32 %0, %1, %2" : "=v"(bw3) : "v"(y[6]), "v"(y[7]));
                union { unsigned u[4]; short8 v; } bu;
                bu.u[0] = bw0; bu.u[1] = bw1; bu.u[2] = bw2; bu.u[3] = bw3;
                floatx4 acc0 = __builtin_amdgcn_mfma_f32_16x16x32_bf16(
                    af0, bu.v, (floatx4){c0p[0], c0p[1], c0p[2], c0p[3]}, 0, 0, 0);
                floatx4 acc1 = __builtin_amdgcn_mfma_f32_16x16x32_bf16(
                    af1, bu.v, (floatx4){c0p[4], c0p[5], c0p[6], c0p[7]}, 0, 0, 0);

                // neighbor row r+1 via DPP; 16-row tile boundary via LDS strip
                float nx[8];
                #pragma unroll
                for (int q = 0; q < 8; ++q) nx[q] = dpp_shl1(y[q]);
                float lbr = __int_as_float(__builtin_amdgcn_ds_bpermute(pidx, __float_as_int(y[0])));
                float lb  = (hi == 3) ? 0.f : lbr;    // row r, col hi*8+8
                float xb  = dpp_shl1(lb);             // row r+1, col hi*8+8
                if (hi == 3) xb = 0.f;
                if (lr == 15) {
                    float4 n0 = *reinterpret_cast<const float4*>(&brow[cur][rt + 1][hi * 8]);
                    float4 n1 = *reinterpret_cast<const float4*>(&brow[cur][rt + 1][hi * 8 + 4]);
                    nx[0] = n0.x; nx[1] = n0.y; nx[2] = n0.z; nx[3] = n0.w;
                    nx[4] = n1.x; nx[5] = n1.y; nx[6] = n1.z; nx[7] = n1.w;
                    xb = brow[cur][rt + 1][hi * 8 + 8];   // pad col 32 == 0 for hi==3
                }

                float le[8], xl[8];
                #pragma unroll
                for (int q = 0; q < 7; ++q) { le[q] = y[q + 1]; xl[q] = nx[q + 1]; }
                le[7] = lb; xl[7] = xb;

                #pragma unroll
                for (int q = 0; q < 8; ++q) {
                    float accq = (q < 4) ? acc0[q] : acc1[q - 4];
                    float sm = le[q] + nx[q];
                    float t  = __builtin_amdgcn_fmed3f(sm, 1.f, 2.f);
                    float z  = fmaf(le[q], d1p[q],
                               fmaf(nx[q], w4n[q],
                               fmaf(t, w4c[q],
                               fmaf(xl[q], w3v[q], accq))));
                    y[q] = myrelu(z);
                }
                if (lr == 0) {
                    *reinterpret_cast<float4*>(&brow[cur ^ 1][rt][hi * 8])     = make_float4(y[0], y[1], y[2], y[3]);
                    *reinterpret_cast<float4*>(&brow[cur ^ 1][rt][hi * 8 + 4]) = make_float4(y[4], y[5], y[6], y[7]);
                }
            }
            __syncthreads();
        }
        if (p == NPHASE - 1) break;

        // ---- phase boundary: publish rows 0..31 to left neighbor; reload halo ----
        if (rt < CH / 16 && c > 0) {
            unsigned long long* gp =
                reinterpret_cast<unsigned long long*>(gs + (size_t)t0 * KK + hi * 8);
            union { float f[8]; unsigned long long u[4]; } pk;
            #pragma unroll
            for (int q = 0; q < 8; ++q) pk.f[q] = y[q];
            #pragma unroll
            for (int w = 0; w < 4; ++w)
                __hip_atomic_store(&gp[w], pk.u[w], __ATOMIC_RELAXED, __HIP_MEMORY_SCOPE_AGENT);
        }
        __syncthreads();
        if (tid == 0) {
            if (c > 0)
                __hip_atomic_store(&flags[b * BPB + c], p + 1,
                                   __ATOMIC_RELEASE, __HIP_MEMORY_SCOPE_AGENT);
            if (c < BPB - 1) {
                while (__hip_atomic_load(&flags[b * BPB + c + 1],
                                         __ATOMIC_ACQUIRE, __HIP_MEMORY_SCOPE_AGENT) < p + 1)
                    __builtin_amdgcn_s_sleep(2);
            }
        }
        __syncthreads();
        if (active && rt >= CH / 16) {      // halo waves 2,3 reload fresh rows
            unsigned long long* gp =
                reinterpret_cast<unsigned long long*>(gs + (size_t)t0 * KK + hi * 8);
            union { float f[8]; unsigned long long u[4]; } pk;
            #pragma unroll
            for (int w = 0; w < 4; ++w)
                pk.u[w] = __hip_atomic_load(&gp[w], __ATOMIC_RELAXED, __HIP_MEMORY_SCOPE_AGENT);
            #pragma unroll
            for (int q = 0; q < 8; ++q) y[q] = pk.f[q];
            if (lr == 0) {
                *reinterpret_cast<float4*>(&brow[0][rt][hi * 8])     = make_float4(y[0], y[1], y[2], y[3]);
                *reinterpret_cast<float4*>(&brow[0][rt][hi * 8 + 4]) = make_float4(y[4], y[5], y[6], y[7]);
            }
        }
        __syncthreads();
    }

    // epilogue: sigmoid + store (chunk waves 0..1 only)
    if (rt < CH / 16) {
        float* op = out + ((size_t)b * TT + t0) * KK + hi * 8;
        float o[8];
        #pragma unroll
        for (int q = 0; q < 8; ++q)
            o[q] = 1.f / (1.f + __expf(-5.f * (y[q] - 0.5f)));
        *reinterpret_cast<float4*>(&op[0]) = make_float4(o[0], o[1], o[2], o[3]);
        *reinterpret_cast<float4*>(&op[4]) = make_float4(o[4], o[5], o[6], o[7]);
    }
}

extern "C" void kernel_launch(void* const* d_in, const int* in_sizes, int n_in,
                              void* d_out, int out_size, void* d_ws, size_t ws_size,
                              hipStream_t stream) {
    const float* x       = (const float*)d_in[0];
    const float* w_right = (const float*)d_in[1];
    const float* w_op    = (const float*)d_in[2];
    float* ws  = (float*)d_ws;
    float* out = (float*)d_out;

    prep_kernel<<<1, 64, 0, stream>>>(w_right, w_op, ws);
    atomx_kernel<<<BB * TT / 8, 256, 0, stream>>>(x, ws);

    void* args[] = { (void*)&ws, (void*)&out };
    hipLaunchCooperativeKernel((void*)phase_all_kernel,
                               dim3(BB * BPB), dim3(256), args, 0, stream);
}